// Round 5
// baseline (225.026 us; speedup 1.0000x reference)
//
#include <hip/hip_runtime.h>
#include <hip/hip_bf16.h>

typedef unsigned short ushortT;
typedef unsigned int uintT;
typedef __attribute__((ext_vector_type(8))) short short8;
typedef __attribute__((ext_vector_type(4))) float f32x4;

#define BATCH   2048
#define NELEC   64
#define BN_EPS  1e-5f

// ws layout (float offsets)
#define OFF_AMEAN  4096                 // 64
#define OFF_SS1    4160                 // scale1[64], shift1[64]
#define OFF_SS2    4288                 // scale2[128], shift2[128]
#define OFF_PS1    4544                 // [64 slots][64] sums
#define OFF_PQ1    8640                 // [64][64] sumsq
#define OFF_PS2    12736                // [64][128]
#define OFF_PQ2    20928                // [64][128]  (ends 29120)
#define OFF_ABF    29120                // ushort: A_hi[4096], A_lo[4096]   (A[n][m])
#define OFF_W1T    33216                // ushort: W1t_hi[4096], W1t_lo[4096]  (W1t[o][k])
#define OFF_W2T    37312                // ushort: W2t_hi[8192], W2t_lo[8192]  (W2t[o][k])
#define OFF_H1     45504                // ushort h1[b][n][o]  bf16, 2048*64*64
#define OFF_T1     4239808              // ushort T1[b][o][n]  bf16, 2048*64*64
#define OFF_T2     4239808              // ushort T2[b][o][n]  bf16, 2048*128*64 (reuses T1, extends past it)
#define OFF_H2     12628416             // ushort h2[b][n][o]  bf16, 2048*64*128

#define MFMA(a, b, c) __builtin_amdgcn_mfma_f32_16x16x32_bf16(a, b, c, 0, 0, 0)

__device__ inline float bf2f(ushortT u) { return __uint_as_float(((uintT)u) << 16); }
__device__ inline ushortT f2bf(float f) {
  uintT u = __float_as_uint(f);
  u = (u + 0x7FFFu + ((u >> 16) & 1u)) >> 16;
  return (ushortT)u;
}
// round-split (prep only)
__device__ inline void split2(float f, ushortT& hi, ushortT& lo) {
  hi = f2bf(f);
  lo = f2bf(f - bf2f(hi));
}
// truncation split: hi = trunc bits (exact residual), lo = rounded residual
__device__ inline void splitT8(const float* f, short8& hi, short8& lo) {
  #pragma unroll
  for (int e = 0; e < 8; ++e) {
    uintT u = __float_as_uint(f[e]);
    float fh = __uint_as_float(u & 0xFFFF0000u);
    hi[e] = (short)(u >> 16);
    lo[e] = (short)f2bf(f[e] - fh);
  }
}

// ---------------- prep: build A (bf16 hi/lo), amean, W1t/W2t hi/lo ----------------
__global__ __launch_bounds__(256) void prep_kernel(const int* __restrict__ src,
    const int* __restrict__ dst, int E,
    const float* __restrict__ W1, const float* __restrict__ W2,
    float* __restrict__ ws) {
  __shared__ float degS[NELEC];
  __shared__ float As[NELEC * NELEC];
  int t = threadIdx.x;
  if (t < NELEC) degS[t] = 1.0f;               // self-loop
  for (int i = t; i < NELEC * NELEC; i += 256) As[i] = 0.0f;
  __syncthreads();
  for (int e = t; e < E; e += 256) atomicAdd(&degS[dst[e]], 1.0f);
  __syncthreads();
  for (int e = t; e < E; e += 256) {
    float en = rsqrtf(degS[src[e]]) * rsqrtf(degS[dst[e]]);
    atomicAdd(&As[dst[e] * NELEC + src[e]], en);
  }
  __syncthreads();
  if (t < NELEC) As[t * NELEC + t] += 1.0f / degS[t];
  __syncthreads();
  ushortT* abf = (ushortT*)(ws + OFF_ABF);
  for (int i = t; i < 4096; i += 256) {
    ushortT hi, lo; split2(As[i], hi, lo);
    abf[i] = hi; abf[4096 + i] = lo;
  }
  if (t < NELEC) {
    float s = 0.0f;
    for (int n = 0; n < NELEC; ++n) s += As[n * NELEC + t];
    ws[OFF_AMEAN + t] = s * (1.0f / NELEC);
  }
  ushortT* w1t = (ushortT*)(ws + OFF_W1T);
  for (int i = t; i < 4096; i += 256) {
    int o = i >> 6, k = i & 63;
    ushortT hi, lo; split2(W1[k * 64 + o], hi, lo);
    w1t[i] = hi; w1t[4096 + i] = lo;
  }
  ushortT* w2t = (ushortT*)(ws + OFF_W2T);
  for (int i = t; i < 8192; i += 256) {
    int o = i >> 6, k = i & 63;
    ushortT hi, lo; split2(W2[k * 128 + o], hi, lo);
    w2t[i] = hi; w2t[8192 + i] = lo;
  }
}

// ---------------- wgemm1: T1[b][o][n] = (X[b] @ W1)^storedT  (wave = item, no LDS) ----------------
__global__ __launch_bounds__(256) void wgemm1_kernel(const float* __restrict__ x,
    float* __restrict__ ws) {
  const int t = threadIdx.x, w = t >> 6, lane = t & 63;
  const int c = lane & 15, g = lane >> 4;
  const int b = blockIdx.x * 4 + w;
  const ushortT* w1t = (const ushortT*)(ws + OFF_W1T);
  ushortT* t1 = (ushortT*)(ws + OFF_T1) + (size_t)b * 4096;

  // X fragments (A-operand rows n), trunc-split hi/lo
  short8 Xh[4][2], Xl[4][2];
  #pragma unroll
  for (int rt = 0; rt < 4; ++rt) {
    #pragma unroll
    for (int ks = 0; ks < 2; ++ks) {
      const float* p = x + (size_t)b * 4096 + (rt * 16 + c) * 64 + ks * 32 + g * 8;
      float4 fa = *(const float4*)p, fb = *(const float4*)(p + 4);
      float f[8] = {fa.x, fa.y, fa.z, fa.w, fb.x, fb.y, fb.z, fb.w};
      splitT8(f, Xh[rt][ks], Xl[rt][ks]);
    }
  }
  #pragma unroll
  for (int s = 0; s < 4; ++s) {
    f32x4 acc[4] = {{0,0,0,0},{0,0,0,0},{0,0,0,0},{0,0,0,0}};
    #pragma unroll
    for (int ks = 0; ks < 2; ++ks) {
      short8 bh = *(const short8*)(w1t + (s * 16 + c) * 64 + ks * 32 + g * 8);
      short8 bl = *(const short8*)(w1t + 4096 + (s * 16 + c) * 64 + ks * 32 + g * 8);
      #pragma unroll
      for (int rt = 0; rt < 4; ++rt) {
        acc[rt] = MFMA(Xh[rt][ks], bh, acc[rt]);
        acc[rt] = MFMA(Xh[rt][ks], bl, acc[rt]);
        acc[rt] = MFMA(Xl[rt][ks], bh, acc[rt]);
      }
    }
    // store: lane holds rows n = rt*16+4g+r, col o = s*16+c  ->  T1[b][o][n]
    #pragma unroll
    for (int rt = 0; rt < 4; ++rt) {
      uint2 pk;
      pk.x = (uintT)f2bf(acc[rt][0]) | ((uintT)f2bf(acc[rt][1]) << 16);
      pk.y = (uintT)f2bf(acc[rt][2]) | ((uintT)f2bf(acc[rt][3]) << 16);
      *(uint2*)(t1 + (s * 16 + c) * 64 + rt * 16 + 4 * g) = pk;
    }
  }
}

// ---------------- agemm1: h1[b][n][o] = A @ T1[b] + b1, fused BN stats (swapped mfma) ----------------
__global__ __launch_bounds__(256) void agemm1_kernel(const float* __restrict__ b1,
    float* __restrict__ ws) {
  const int t = threadIdx.x, w = t >> 6, lane = t & 63;
  const int c = lane & 15, g = lane >> 4;
  const int wg = blockIdx.x * 4 + w;
  const int ns = wg & 3;               // n-strip
  const int b0 = (wg >> 2) * 2;        // 2 items per wave
  const ushortT* abf = (const ushortT*)(ws + OFF_ABF);
  // B-frag: A^T cols n = ns*16+c, k = m
  short8 Bh[2], Bl[2];
  #pragma unroll
  for (int ks = 0; ks < 2; ++ks) {
    Bh[ks] = *(const short8*)(abf + (ns * 16 + c) * 64 + ks * 32 + g * 8);
    Bl[ks] = *(const short8*)(abf + 4096 + (ns * 16 + c) * 64 + ks * 32 + g * 8);
  }
  float Sa[4][4] = {}, Qa[4][4] = {};
  #pragma unroll
  for (int ib = 0; ib < 2; ++ib) {
    const int b = b0 + ib;
    const ushortT* t1 = (const ushortT*)(ws + OFF_T1) + (size_t)b * 4096;
    ushortT* h1 = (ushortT*)(ws + OFF_H1) + (size_t)b * 4096;
    #pragma unroll
    for (int rt = 0; rt < 4; ++rt) {
      f32x4 acc = {0, 0, 0, 0};
      #pragma unroll
      for (int ks = 0; ks < 2; ++ks) {
        short8 tf = *(const short8*)(t1 + (rt * 16 + c) * 64 + ks * 32 + g * 8);
        acc = MFMA(tf, Bh[ks], acc);
        acc = MFMA(tf, Bl[ks], acc);
      }
      float4 bv = *(const float4*)(b1 + rt * 16 + 4 * g);
      float v0 = acc[0] + bv.x, v1 = acc[1] + bv.y;
      float v2 = acc[2] + bv.z, v3 = acc[3] + bv.w;
      Sa[rt][0] += v0; Qa[rt][0] += v0 * v0;
      Sa[rt][1] += v1; Qa[rt][1] += v1 * v1;
      Sa[rt][2] += v2; Qa[rt][2] += v2 * v2;
      Sa[rt][3] += v3; Qa[rt][3] += v3 * v3;
      uint2 pk;
      pk.x = (uintT)f2bf(v0) | ((uintT)f2bf(v1) << 16);
      pk.y = (uintT)f2bf(v2) | ((uintT)f2bf(v3) << 16);
      // lane holds rows o = rt*16+4g+r, col n = ns*16+c -> h1[b][n][o]
      *(uint2*)(h1 + (ns * 16 + c) * 64 + rt * 16 + 4 * g) = pk;
    }
  }
  // reduce stats over the 16 c-lanes, then atomics from c==0 lanes
  const int slot = blockIdx.x & 63;
  #pragma unroll
  for (int rt = 0; rt < 4; ++rt) {
    #pragma unroll
    for (int r = 0; r < 4; ++r) {
      float S = Sa[rt][r], Q = Qa[rt][r];
      S += __shfl_xor(S, 1); S += __shfl_xor(S, 2);
      S += __shfl_xor(S, 4); S += __shfl_xor(S, 8);
      Q += __shfl_xor(Q, 1); Q += __shfl_xor(Q, 2);
      Q += __shfl_xor(Q, 4); Q += __shfl_xor(Q, 8);
      if (c == 0) {
        const int ch = rt * 16 + 4 * g + r;
        atomicAdd(&ws[OFF_PS1 + slot * 64 + ch], S);
        atomicAdd(&ws[OFF_PQ1 + slot * 64 + ch], Q);
      }
    }
  }
}

// ---------------- BN finalize ----------------
__global__ void reduce1_kernel(const float* __restrict__ g1, const float* __restrict__ be1,
                               float* __restrict__ ws) {
  int t = threadIdx.x;
  if (t < 64) {
    float S = 0.0f, Q = 0.0f;
    for (int s = 0; s < 64; ++s) { S += ws[OFF_PS1 + s * 64 + t]; Q += ws[OFF_PQ1 + s * 64 + t]; }
    const float inv = 1.0f / (float)(BATCH * NELEC);
    float m = S * inv;
    float v = fmaxf(Q * inv - m * m, 0.0f);
    float sc = g1[t] * rsqrtf(v + BN_EPS);
    ws[OFF_SS1 + t] = sc;
    ws[OFF_SS1 + 64 + t] = fmaf(-m, sc, be1[t]);
  }
}

__global__ void reduce2_kernel(const float* __restrict__ g2, const float* __restrict__ be2,
                               float* __restrict__ ws) {
  int t = threadIdx.x;
  if (t < 128) {
    float S = 0.0f, Q = 0.0f;
    for (int s = 0; s < 64; ++s) { S += ws[OFF_PS2 + s * 128 + t]; Q += ws[OFF_PQ2 + s * 128 + t]; }
    const float inv = 1.0f / (float)(BATCH * NELEC);
    float m = S * inv;
    float v = fmaxf(Q * inv - m * m, 0.0f);
    float sc = g2[t] * rsqrtf(v + BN_EPS);
    ws[OFF_SS2 + t] = sc;
    ws[OFF_SS2 + 128 + t] = fmaf(-m, sc, be2[t]);
  }
}

// ---------------- wgemm2: T2[b][o][n] = relu(bn1(h1[b])) @ W2  (wave = item) ----------------
__global__ __launch_bounds__(256) void wgemm2_kernel(float* __restrict__ ws) {
  const int t = threadIdx.x, w = t >> 6, lane = t & 63;
  const int c = lane & 15, g = lane >> 4;
  const int b = blockIdx.x * 4 + w;
  const ushortT* w2t = (const ushortT*)(ws + OFF_W2T);
  const ushortT* h1 = (const ushortT*)(ws + OFF_H1) + (size_t)b * 4096;
  ushortT* t2 = (ushortT*)(ws + OFF_T2) + (size_t)b * 8192;

  // per-lane BN scale/shift for its k-slots (uniform across items)
  float s1v[2][8], t1v[2][8];
  #pragma unroll
  for (int ks = 0; ks < 2; ++ks) {
    const float* sp = ws + OFF_SS1 + ks * 32 + g * 8;
    const float* tp = ws + OFF_SS1 + 64 + ks * 32 + g * 8;
    float4 sa = *(const float4*)sp, sb = *(const float4*)(sp + 4);
    float4 ta = *(const float4*)tp, tb = *(const float4*)(tp + 4);
    s1v[ks][0]=sa.x; s1v[ks][1]=sa.y; s1v[ks][2]=sa.z; s1v[ks][3]=sa.w;
    s1v[ks][4]=sb.x; s1v[ks][5]=sb.y; s1v[ks][6]=sb.z; s1v[ks][7]=sb.w;
    t1v[ks][0]=ta.x; t1v[ks][1]=ta.y; t1v[ks][2]=ta.z; t1v[ks][3]=ta.w;
    t1v[ks][4]=tb.x; t1v[ks][5]=tb.y; t1v[ks][6]=tb.z; t1v[ks][7]=tb.w;
  }
  // Y = relu(bn(h1)) fragments, trunc-split
  short8 Yh[4][2], Yl[4][2];
  #pragma unroll
  for (int rt = 0; rt < 4; ++rt) {
    #pragma unroll
    for (int ks = 0; ks < 2; ++ks) {
      short8 hv = *(const short8*)(h1 + (rt * 16 + c) * 64 + ks * 32 + g * 8);
      float f[8];
      #pragma unroll
      for (int e = 0; e < 8; ++e)
        f[e] = fmaxf(fmaf(bf2f((ushortT)hv[e]), s1v[ks][e], t1v[ks][e]), 0.0f);
      splitT8(f, Yh[rt][ks], Yl[rt][ks]);
    }
  }
  #pragma unroll
  for (int s = 0; s < 8; ++s) {
    f32x4 acc[4] = {{0,0,0,0},{0,0,0,0},{0,0,0,0},{0,0,0,0}};
    #pragma unroll
    for (int ks = 0; ks < 2; ++ks) {
      short8 bh = *(const short8*)(w2t + (s * 16 + c) * 64 + ks * 32 + g * 8);
      short8 bl = *(const short8*)(w2t + 8192 + (s * 16 + c) * 64 + ks * 32 + g * 8);
      #pragma unroll
      for (int rt = 0; rt < 4; ++rt) {
        acc[rt] = MFMA(Yh[rt][ks], bh, acc[rt]);
        acc[rt] = MFMA(Yh[rt][ks], bl, acc[rt]);
        acc[rt] = MFMA(Yl[rt][ks], bh, acc[rt]);
      }
    }
    #pragma unroll
    for (int rt = 0; rt < 4; ++rt) {
      uint2 pk;
      pk.x = (uintT)f2bf(acc[rt][0]) | ((uintT)f2bf(acc[rt][1]) << 16);
      pk.y = (uintT)f2bf(acc[rt][2]) | ((uintT)f2bf(acc[rt][3]) << 16);
      *(uint2*)(t2 + (s * 16 + c) * 64 + rt * 16 + 4 * g) = pk;
    }
  }
}

// ---------------- agemm2: h2[b][n][o] = A @ T2[b] + b2, fused BN stats ----------------
__global__ __launch_bounds__(256) void agemm2_kernel(const float* __restrict__ b2,
    float* __restrict__ ws) {
  const int t = threadIdx.x, w = t >> 6, lane = t & 63;
  const int c = lane & 15, g = lane >> 4;
  const int wg = blockIdx.x * 4 + w;
  const int ns = wg & 3;
  const int b0 = (wg >> 2) * 2;
  const ushortT* abf = (const ushortT*)(ws + OFF_ABF);
  short8 Bh[2], Bl[2];
  #pragma unroll
  for (int ks = 0; ks < 2; ++ks) {
    Bh[ks] = *(const short8*)(abf + (ns * 16 + c) * 64 + ks * 32 + g * 8);
    Bl[ks] = *(const short8*)(abf + 4096 + (ns * 16 + c) * 64 + ks * 32 + g * 8);
  }
  float Sa[8][4] = {}, Qa[8][4] = {};
  #pragma unroll
  for (int ib = 0; ib < 2; ++ib) {
    const int b = b0 + ib;
    const ushortT* t2 = (const ushortT*)(ws + OFF_T2) + (size_t)b * 8192;
    ushortT* h2 = (ushortT*)(ws + OFF_H2) + (size_t)b * 8192;
    #pragma unroll
    for (int rt = 0; rt < 8; ++rt) {
      f32x4 acc = {0, 0, 0, 0};
      #pragma unroll
      for (int ks = 0; ks < 2; ++ks) {
        short8 tf = *(const short8*)(t2 + (rt * 16 + c) * 64 + ks * 32 + g * 8);
        acc = MFMA(tf, Bh[ks], acc);
        acc = MFMA(tf, Bl[ks], acc);
      }
      float4 bv = *(const float4*)(b2 + rt * 16 + 4 * g);
      float v0 = acc[0] + bv.x, v1 = acc[1] + bv.y;
      float v2 = acc[2] + bv.z, v3 = acc[3] + bv.w;
      Sa[rt][0] += v0; Qa[rt][0] += v0 * v0;
      Sa[rt][1] += v1; Qa[rt][1] += v1 * v1;
      Sa[rt][2] += v2; Qa[rt][2] += v2 * v2;
      Sa[rt][3] += v3; Qa[rt][3] += v3 * v3;
      uint2 pk;
      pk.x = (uintT)f2bf(v0) | ((uintT)f2bf(v1) << 16);
      pk.y = (uintT)f2bf(v2) | ((uintT)f2bf(v3) << 16);
      *(uint2*)(h2 + (ns * 16 + c) * 128 + rt * 16 + 4 * g) = pk;
    }
  }
  const int slot = blockIdx.x & 63;
  #pragma unroll
  for (int rt = 0; rt < 8; ++rt) {
    #pragma unroll
    for (int r = 0; r < 4; ++r) {
      float S = Sa[rt][r], Q = Qa[rt][r];
      S += __shfl_xor(S, 1); S += __shfl_xor(S, 2);
      S += __shfl_xor(S, 4); S += __shfl_xor(S, 8);
      Q += __shfl_xor(Q, 1); Q += __shfl_xor(Q, 2);
      Q += __shfl_xor(Q, 4); Q += __shfl_xor(Q, 8);
      if (c == 0) {
        const int ch = rt * 16 + 4 * g + r;
        atomicAdd(&ws[OFF_PS2 + slot * 128 + ch], S);
        atomicAdd(&ws[OFF_PQ2 + slot * 128 + ch], Q);
      }
    }
  }
}

// ---------------- layer 3 (+ mean pool): out[b] = (amean@relu(bn2(h2[b])))@W3 + b3 ----------------
__global__ __launch_bounds__(256) void layer3_kernel(const float* __restrict__ W3,
    const float* __restrict__ b3, const float* __restrict__ ws,
    float* __restrict__ out) {
  const int w = threadIdx.x >> 6, lane = threadIdx.x & 63;
  const int item = blockIdx.x * 4 + w;
  const int f0 = lane * 2;
  const float s2a = ws[OFF_SS2 + f0],       s2b = ws[OFF_SS2 + f0 + 1];
  const float t2a = ws[OFF_SS2 + 128 + f0], t2b = ws[OFF_SS2 + 128 + f0 + 1];
  const float* am = ws + OFF_AMEAN;
  const ushortT* h2 = (const ushortT*)(ws + OFF_H2) + (size_t)item * 8192;
  float v0 = 0.0f, v1 = 0.0f;
  #pragma unroll 8
  for (int m = 0; m < 64; ++m) {
    uintT pk = *(const uintT*)(h2 + m * 128 + f0);
    float y0 = fmaxf(fmaf(bf2f((ushortT)(pk & 0xffffu)), s2a, t2a), 0.0f);
    float y1 = fmaxf(fmaf(bf2f((ushortT)(pk >> 16)),     s2b, t2b), 0.0f);
    float a = am[m];
    v0 = fmaf(a, y0, v0);
    v1 = fmaf(a, y1, v1);
  }
  float o0 = b3[f0], o1 = b3[f0 + 1];
  #pragma unroll 8
  for (int k = 0; k < 128; ++k) {
    float vk = __shfl((k & 1) ? v1 : v0, k >> 1, 64);
    o0 = fmaf(vk, W3[k * 128 + f0],     o0);
    o1 = fmaf(vk, W3[k * 128 + f0 + 1], o1);
  }
  float2 ov; ov.x = o0; ov.y = o1;
  *(float2*)(out + (size_t)item * 128 + f0) = ov;
}

extern "C" void kernel_launch(void* const* d_in, const int* in_sizes, int n_in,
                              void* d_out, int out_size, void* d_ws, size_t ws_size,
                              hipStream_t stream) {
  const float* x   = (const float*)d_in[0];
  const float* W1  = (const float*)d_in[1];
  const float* b1  = (const float*)d_in[2];
  const float* W2  = (const float*)d_in[3];
  const float* b2  = (const float*)d_in[4];
  const float* W3  = (const float*)d_in[5];
  const float* b3  = (const float*)d_in[6];
  const float* g1  = (const float*)d_in[7];
  const float* be1 = (const float*)d_in[8];
  const float* g2  = (const float*)d_in[9];
  const float* be2 = (const float*)d_in[10];
  const int*   src = (const int*)d_in[11];
  const int*   dst = (const int*)d_in[12];
  const int E = in_sizes[11];
  float* ws  = (float*)d_ws;
  float* out = (float*)d_out;

  // zero BN partial-stat slots (PS1..PQ2)
  hipMemsetAsync((void*)(ws + OFF_PS1), 0, (size_t)(29120 - OFF_PS1) * 4, stream);
  hipLaunchKernelGGL(prep_kernel,   dim3(1),    dim3(256), 0, stream, src, dst, E, W1, W2, ws);
  hipLaunchKernelGGL(wgemm1_kernel, dim3(512),  dim3(256), 0, stream, x, ws);
  hipLaunchKernelGGL(agemm1_kernel, dim3(1024), dim3(256), 0, stream, b1, ws);
  hipLaunchKernelGGL(reduce1_kernel,dim3(1),    dim3(64),  0, stream, g1, be1, ws);
  hipLaunchKernelGGL(wgemm2_kernel, dim3(512),  dim3(256), 0, stream, ws);
  hipLaunchKernelGGL(agemm2_kernel, dim3(1024), dim3(256), 0, stream, b2, ws);
  hipLaunchKernelGGL(reduce2_kernel,dim3(1),    dim3(128), 0, stream, g2, be2, ws);
  hipLaunchKernelGGL(layer3_kernel, dim3(512),  dim3(256), 0, stream, W3, b3, ws, out);
}

// Round 7
// 186.163 us; speedup vs baseline: 1.2088x; 1.2088x over previous
//
#include <hip/hip_runtime.h>
#include <hip/hip_bf16.h>

typedef unsigned short ushortT;
typedef unsigned int uintT;
typedef __attribute__((ext_vector_type(8))) short short8;
typedef __attribute__((ext_vector_type(4))) float f32x4;

#define BATCH   2048
#define NELEC   64
#define BN_EPS  1e-5f

// ws float-offset layout (stats/coeff region)
#define OFF_AMEAN  4096
#define OFF_SS1    4160                 // scale1[64], shift1[64]
#define OFF_SS2    4288                 // scale2[128], shift2[128]
#define OFF_PS1    4544                 // [64 slots][64]
#define OFF_PQ1    8640
#define OFF_PS2    12736                // [64 slots][128]
#define OFF_PQ2    20928                // ends 29120
// ushort region U = (ushortT*)(ws + 29120):
//   A72:  hi[64][72], lo[64][72]           @ U + 0      (9216)
//   W1T:  hi[64][72], lo[64][72]           @ U + 9216   (9216)   W1t[o][k]
//   W2T:  hi[128][72], lo[128][72]         @ U + 18432  (18432)  W2t[o][k]
//   H1:   [2048][64][64] bf16              @ U + 36864
//   H2:   [2048][64][128] bf16             @ U + 36864 + 8388608
#define UOFF_A     0
#define UOFF_W1T   9216
#define UOFF_W2T   18432
#define UOFF_H1    36864
#define UOFF_H2    (36864 + 8388608)

#define MFMA(a, b, c) __builtin_amdgcn_mfma_f32_16x16x32_bf16(a, b, c, 0, 0, 0)

__device__ inline float bf2f(ushortT u) { return __uint_as_float(((uintT)u) << 16); }
__device__ inline ushortT f2bf(float f) {
  uintT u = __float_as_uint(f);
  u = (u + 0x7FFFu + ((u >> 16) & 1u)) >> 16;
  return (ushortT)u;
}
__device__ inline void split2(float f, ushortT& hi, ushortT& lo) {
  hi = f2bf(f);
  lo = f2bf(f - bf2f(hi));
}
// truncation split: hi = trunc bits (exact residual), lo = rounded residual
__device__ inline void splitT8(const float* f, short8& hi, short8& lo) {
  #pragma unroll
  for (int e = 0; e < 8; ++e) {
    uintT u = __float_as_uint(f[e]);
    float fh = __uint_as_float(u & 0xFFFF0000u);
    hi[e] = (short)(u >> 16);
    lo[e] = (short)f2bf(f[e] - fh);
  }
}
__device__ inline uint2 pack4(f32x4 v) {
  uint2 pk;
  pk.x = (uintT)f2bf(v[0]) | ((uintT)f2bf(v[1]) << 16);
  pk.y = (uintT)f2bf(v[2]) | ((uintT)f2bf(v[3]) << 16);
  return pk;
}

// ---------------- prep: A72/W1T/W2T (stride-72 padded, hi/lo), amean ----------------
__global__ __launch_bounds__(256) void prep_kernel(const int* __restrict__ src,
    const int* __restrict__ dst, int E,
    const float* __restrict__ W1, const float* __restrict__ W2,
    float* __restrict__ ws) {
  __shared__ float degS[NELEC];
  __shared__ float As[NELEC * NELEC];
  int t = threadIdx.x;
  if (t < NELEC) degS[t] = 1.0f;               // self-loop
  for (int i = t; i < NELEC * NELEC; i += 256) As[i] = 0.0f;
  __syncthreads();
  for (int e = t; e < E; e += 256) atomicAdd(&degS[dst[e]], 1.0f);
  __syncthreads();
  for (int e = t; e < E; e += 256) {
    float en = rsqrtf(degS[src[e]]) * rsqrtf(degS[dst[e]]);
    atomicAdd(&As[dst[e] * NELEC + src[e]], en);
  }
  __syncthreads();
  if (t < NELEC) As[t * NELEC + t] += 1.0f / degS[t];
  __syncthreads();
  ushortT* U = (ushortT*)(ws + 29120);
  ushortT* a72 = U + UOFF_A;
  for (int i = t; i < 4096; i += 256) {
    int row = i >> 6, k = i & 63;
    ushortT hi, lo; split2(As[i], hi, lo);
    a72[row * 72 + k] = hi; a72[4608 + row * 72 + k] = lo;
  }
  if (t < NELEC) {
    float s = 0.0f;
    for (int n = 0; n < NELEC; ++n) s += As[n * NELEC + t];
    ws[OFF_AMEAN + t] = s * (1.0f / NELEC);
  }
  ushortT* w1t = U + UOFF_W1T;
  for (int i = t; i < 4096; i += 256) {
    int o = i >> 6, k = i & 63;
    ushortT hi, lo; split2(W1[k * 64 + o], hi, lo);
    w1t[o * 72 + k] = hi; w1t[4608 + o * 72 + k] = lo;
  }
  ushortT* w2t = U + UOFF_W2T;
  for (int i = t; i < 8192; i += 256) {
    int o = i >> 6, k = i & 63;
    ushortT hi, lo; split2(W2[k * 128 + o], hi, lo);
    w2t[o * 72 + k] = hi; w2t[9216 + o * 72 + k] = lo;
  }
}

// ---------------- layer 1 fused: h1[b][n][o] = A*(X@W1)+b1, TB=8 items, 8 waves ----------------
__global__ __launch_bounds__(512, 2) void layer1_fused(const float* __restrict__ x,
    const float* __restrict__ b1, float* __restrict__ ws) {
  __shared__ ushortT Wl[9216];     // W1t hi[64][72], lo[64][72]
  __shared__ ushortT Tt[36864];    // 8 items × [64 o][72]; reused as Hbuf [64 n'][72]
  const int t = threadIdx.x;
  ushortT* U = (ushortT*)(ws + 29120);
  // stage W1 (hi/lo) to LDS
  for (int i = t; i < 1152; i += 512)
    ((uint4*)Wl)[i] = ((const uint4*)(U + UOFF_W1T))[i];
  const int w = t >> 6, lane = t & 63, c = lane & 15, g = lane >> 4;
  const int b = blockIdx.x * 8 + w;   // wave = item
  // X fragments (rows n = nq*16+c), trunc hi/lo split
  short8 Xh[4][2], Xl[4][2];
  #pragma unroll
  for (int nq = 0; nq < 4; ++nq) {
    #pragma unroll
    for (int ks = 0; ks < 2; ++ks) {
      const float* p = x + (size_t)b * 4096 + (nq * 16 + c) * 64 + ks * 32 + g * 8;
      float4 fa = *(const float4*)p, fb = *(const float4*)(p + 4);
      float f[8] = {fa.x, fa.y, fa.z, fa.w, fb.x, fb.y, fb.z, fb.w};
      splitT8(f, Xh[nq][ks], Xl[nq][ks]);
    }
  }
  __syncthreads();
  // W-phase: T = X @ W1, 16 independent accs
  f32x4 acc[4][4];
  #pragma unroll
  for (int i = 0; i < 4; ++i)
    #pragma unroll
    for (int j = 0; j < 4; ++j) acc[i][j] = (f32x4){0.f, 0.f, 0.f, 0.f};
  #pragma unroll
  for (int ot = 0; ot < 4; ++ot) {
    #pragma unroll
    for (int ks = 0; ks < 2; ++ks) {
      short8 bh = *(const short8*)&Wl[(ot * 16 + c) * 72 + ks * 32 + g * 8];
      short8 bl = *(const short8*)&Wl[4608 + (ot * 16 + c) * 72 + ks * 32 + g * 8];
      #pragma unroll
      for (int nq = 0; nq < 4; ++nq) {
        acc[nq][ot] = MFMA(Xh[nq][ks], bh, acc[nq][ot]);
        acc[nq][ot] = MFMA(Xh[nq][ks], bl, acc[nq][ot]);
        acc[nq][ot] = MFMA(Xl[nq][ks], bh, acc[nq][ot]);
      }
    }
  }
  // write T_t[o][n] (this wave's item slot only)
  ushortT* tt = &Tt[w * 4608];
  #pragma unroll
  for (int ot = 0; ot < 4; ++ot)
    #pragma unroll
    for (int nq = 0; nq < 4; ++nq)
      *(uint2*)&tt[(ot * 16 + c) * 72 + nq * 16 + 4 * g] = pack4(acc[nq][ot]);
  // A-matrix B-side fragments (registers, from global; L2-hot)
  short8 ABh[4][2], ABl[4][2];
  #pragma unroll
  for (int sp = 0; sp < 4; ++sp)
    #pragma unroll
    for (int ks = 0; ks < 2; ++ks) {
      ABh[sp][ks] = *(const short8*)(U + (sp * 16 + c) * 72 + ks * 32 + g * 8);
      ABl[sp][ks] = *(const short8*)(U + 4608 + (sp * 16 + c) * 72 + ks * 32 + g * 8);
    }
  // A-phase: H^T tiles rows o (rt), cols n' (sp) — verified round-5 orientation
  f32x4 h[4][4];
  #pragma unroll
  for (int i = 0; i < 4; ++i)
    #pragma unroll
    for (int j = 0; j < 4; ++j) h[i][j] = (f32x4){0.f, 0.f, 0.f, 0.f};
  #pragma unroll
  for (int ks = 0; ks < 2; ++ks) {
    short8 af[4];
    #pragma unroll
    for (int rt = 0; rt < 4; ++rt)
      af[rt] = *(const short8*)&tt[(rt * 16 + c) * 72 + ks * 32 + g * 8];
    #pragma unroll
    for (int sp = 0; sp < 4; ++sp)
      #pragma unroll
      for (int rt = 0; rt < 4; ++rt) {
        h[rt][sp] = MFMA(af[rt], ABh[sp][ks], h[rt][sp]);
        h[rt][sp] = MFMA(af[rt], ABl[sp][ks], h[rt][sp]);
      }
  }
  // epilogue: bias, stats, Hbuf (reuse own tt slot; same-wave DS is in-order)
  float Sa[4][4], Qa[4][4];
  #pragma unroll
  for (int i = 0; i < 4; ++i)
    #pragma unroll
    for (int j = 0; j < 4; ++j) { Sa[i][j] = 0.f; Qa[i][j] = 0.f; }
  #pragma unroll
  for (int rt = 0; rt < 4; ++rt) {
    float4 bv = *(const float4*)(b1 + rt * 16 + 4 * g);
    #pragma unroll
    for (int sp = 0; sp < 4; ++sp) {
      f32x4 v;
      v[0] = h[rt][sp][0] + bv.x; v[1] = h[rt][sp][1] + bv.y;
      v[2] = h[rt][sp][2] + bv.z; v[3] = h[rt][sp][3] + bv.w;
      Sa[rt][0] += v[0]; Qa[rt][0] += v[0] * v[0];
      Sa[rt][1] += v[1]; Qa[rt][1] += v[1] * v[1];
      Sa[rt][2] += v[2]; Qa[rt][2] += v[2] * v[2];
      Sa[rt][3] += v[3]; Qa[rt][3] += v[3] * v[3];
      *(uint2*)&tt[(sp * 16 + c) * 72 + rt * 16 + 4 * g] = pack4(v);  // Hbuf[n'][o]
    }
  }
  const int slot = blockIdx.x & 63;
  #pragma unroll
  for (int rt = 0; rt < 4; ++rt)
    #pragma unroll
    for (int r = 0; r < 4; ++r) {
      float S = Sa[rt][r], Q = Qa[rt][r];
      S += __shfl_xor(S, 1); S += __shfl_xor(S, 2); S += __shfl_xor(S, 4); S += __shfl_xor(S, 8);
      Q += __shfl_xor(Q, 1); Q += __shfl_xor(Q, 2); Q += __shfl_xor(Q, 4); Q += __shfl_xor(Q, 8);
      if (c == 0) {
        atomicAdd(&ws[OFF_PS1 + slot * 64 + rt * 16 + 4 * g + r], S);
        atomicAdd(&ws[OFF_PQ1 + slot * 64 + rt * 16 + 4 * g + r], Q);
      }
    }
  __syncthreads();
  // cooperative coalesced store: thread = one (item, n') row of 128B
  {
    const int ib = t >> 6, n2 = t & 63;
    const uint4* srcp = (const uint4*)&Tt[ib * 4608 + n2 * 72];
    uint4* dstp = (uint4*)(U + UOFF_H1 + (size_t)(blockIdx.x * 8 + ib) * 4096 + n2 * 64);
    #pragma unroll
    for (int j = 0; j < 8; ++j) dstp[j] = srcp[j];
  }
}

// ---------------- BN finalize ----------------
__global__ void reduce1_kernel(const float* __restrict__ g1, const float* __restrict__ be1,
                               float* __restrict__ ws) {
  int t = threadIdx.x;
  if (t < 64) {
    float S = 0.0f, Q = 0.0f;
    for (int s = 0; s < 64; ++s) { S += ws[OFF_PS1 + s * 64 + t]; Q += ws[OFF_PQ1 + s * 64 + t]; }
    const float inv = 1.0f / (float)(BATCH * NELEC);
    float m = S * inv;
    float v = fmaxf(Q * inv - m * m, 0.0f);
    float sc = g1[t] * rsqrtf(v + BN_EPS);
    ws[OFF_SS1 + t] = sc;
    ws[OFF_SS1 + 64 + t] = fmaf(-m, sc, be1[t]);
  }
}

__global__ void reduce2_kernel(const float* __restrict__ g2, const float* __restrict__ be2,
                               float* __restrict__ ws) {
  int t = threadIdx.x;
  if (t < 128) {
    float S = 0.0f, Q = 0.0f;
    for (int s = 0; s < 64; ++s) { S += ws[OFF_PS2 + s * 128 + t]; Q += ws[OFF_PQ2 + s * 128 + t]; }
    const float inv = 1.0f / (float)(BATCH * NELEC);
    float m = S * inv;
    float v = fmaxf(Q * inv - m * m, 0.0f);
    float sc = g2[t] * rsqrtf(v + BN_EPS);
    ws[OFF_SS2 + t] = sc;
    ws[OFF_SS2 + 128 + t] = fmaf(-m, sc, be2[t]);
  }
}

// ---------------- layer 2 fused: h2[b][n][o] = A*(relu(bn(h1))@W2)+b2, TB=4, 8 waves ----------------
__global__ __launch_bounds__(512, 2) void layer2_fused(const float* __restrict__ b2,
    float* __restrict__ ws) {
  __shared__ ushortT Wl[18432];    // W2t hi[128][72], lo[128][72]
  __shared__ ushortT Tt[36864];    // 4 items × [128 o][72]; reused as Hbuf [64 n'][136]
  const int t = threadIdx.x;
  ushortT* U = (ushortT*)(ws + 29120);
  for (int i = t; i < 2304; i += 512)
    ((uint4*)Wl)[i] = ((const uint4*)(U + UOFF_W2T))[i];
  const int w = t >> 6, lane = t & 63, c = lane & 15, g = lane >> 4;
  const int b0 = blockIdx.x * 4;
  const ushortT* h1g = U + UOFF_H1;
  // BN coefficients for this lane's k-slots
  float s8[2][8], t8[2][8];
  #pragma unroll
  for (int ks = 0; ks < 2; ++ks) {
    const float* sp_ = ws + OFF_SS1 + ks * 32 + g * 8;
    const float* tp_ = ws + OFF_SS1 + 64 + ks * 32 + g * 8;
    float4 sa = *(const float4*)sp_, sb = *(const float4*)(sp_ + 4);
    float4 ta = *(const float4*)tp_, tb = *(const float4*)(tp_ + 4);
    s8[ks][0]=sa.x; s8[ks][1]=sa.y; s8[ks][2]=sa.z; s8[ks][3]=sa.w;
    s8[ks][4]=sb.x; s8[ks][5]=sb.y; s8[ks][6]=sb.z; s8[ks][7]=sb.w;
    t8[ks][0]=ta.x; t8[ks][1]=ta.y; t8[ks][2]=ta.z; t8[ks][3]=ta.w;
    t8[ks][4]=tb.x; t8[ks][5]=tb.y; t8[ks][6]=tb.z; t8[ks][7]=tb.w;
  }
  // Y = relu(bn(h1)) fragments for the wave's 2 M-subtiles
  short8 Yh[2][2], Yl[2][2];
  #pragma unroll
  for (int si = 0; si < 2; ++si) {
    const int sub = w * 2 + si, ib = sub >> 2, nq = sub & 3;
    #pragma unroll
    for (int ks = 0; ks < 2; ++ks) {
      short8 hv = *(const short8*)(h1g + (size_t)(b0 + ib) * 4096 + (nq * 16 + c) * 64 + ks * 32 + g * 8);
      float f[8];
      #pragma unroll
      for (int e = 0; e < 8; ++e)
        f[e] = fmaxf(fmaf(bf2f((ushortT)hv[e]), s8[ks][e], t8[ks][e]), 0.0f);
      splitT8(f, Yh[si][ks], Yl[si][ks]);
    }
  }
  __syncthreads();
  // W-phase: acc[si][ot], 16 independent chains, 96 MFMA
  f32x4 acc[2][8];
  #pragma unroll
  for (int i = 0; i < 2; ++i)
    #pragma unroll
    for (int j = 0; j < 8; ++j) acc[i][j] = (f32x4){0.f, 0.f, 0.f, 0.f};
  #pragma unroll
  for (int ot = 0; ot < 8; ++ot) {
    #pragma unroll
    for (int ks = 0; ks < 2; ++ks) {
      short8 bh = *(const short8*)&Wl[(ot * 16 + c) * 72 + ks * 32 + g * 8];
      short8 bl = *(const short8*)&Wl[9216 + (ot * 16 + c) * 72 + ks * 32 + g * 8];
      #pragma unroll
      for (int si = 0; si < 2; ++si) {
        acc[si][ot] = MFMA(Yh[si][ks], bh, acc[si][ot]);
        acc[si][ot] = MFMA(Yh[si][ks], bl, acc[si][ot]);
        acc[si][ot] = MFMA(Yl[si][ks], bh, acc[si][ot]);
      }
    }
  }
  #pragma unroll
  for (int si = 0; si < 2; ++si) {
    const int sub = w * 2 + si, ib = sub >> 2, nq = sub & 3;
    #pragma unroll
    for (int ot = 0; ot < 8; ++ot)
      *(uint2*)&Tt[ib * 9216 + (ot * 16 + c) * 72 + nq * 16 + 4 * g] = pack4(acc[si][ot]);
  }
  // A-matrix fragments (registers)
  short8 ABh[4][2], ABl[4][2];
  #pragma unroll
  for (int sp = 0; sp < 4; ++sp)
    #pragma unroll
    for (int ks = 0; ks < 2; ++ks) {
      ABh[sp][ks] = *(const short8*)(U + (sp * 16 + c) * 72 + ks * 32 + g * 8);
      ABl[sp][ks] = *(const short8*)(U + 4608 + (sp * 16 + c) * 72 + ks * 32 + g * 8);
    }
  __syncthreads();
  // A-phase: 2 waves per item, o-halves; rows o (rt), cols n' (sp)
  const int ib = w >> 1, oh = w & 1;
  const ushortT* tt = &Tt[ib * 9216];
  f32x4 h[4][4];
  #pragma unroll
  for (int i = 0; i < 4; ++i)
    #pragma unroll
    for (int j = 0; j < 4; ++j) h[i][j] = (f32x4){0.f, 0.f, 0.f, 0.f};
  #pragma unroll
  for (int ks = 0; ks < 2; ++ks) {
    short8 af[4];
    #pragma unroll
    for (int rt = 0; rt < 4; ++rt)
      af[rt] = *(const short8*)&tt[(oh * 64 + rt * 16 + c) * 72 + ks * 32 + g * 8];
    #pragma unroll
    for (int sp = 0; sp < 4; ++sp)
      #pragma unroll
      for (int rt = 0; rt < 4; ++rt) {
        h[rt][sp] = MFMA(af[rt], ABh[sp][ks], h[rt][sp]);
        h[rt][sp] = MFMA(af[rt], ABl[sp][ks], h[rt][sp]);
      }
  }
  // bias + stats (regs only; Hbuf write deferred until after barrier)
  float Sa[4][4], Qa[4][4];
  #pragma unroll
  for (int i = 0; i < 4; ++i)
    #pragma unroll
    for (int j = 0; j < 4; ++j) { Sa[i][j] = 0.f; Qa[i][j] = 0.f; }
  #pragma unroll
  for (int rt = 0; rt < 4; ++rt) {
    float4 bv = *(const float4*)(b2 + oh * 64 + rt * 16 + 4 * g);
    #pragma unroll
    for (int sp = 0; sp < 4; ++sp) {
      h[rt][sp][0] += bv.x; h[rt][sp][1] += bv.y;
      h[rt][sp][2] += bv.z; h[rt][sp][3] += bv.w;
      Sa[rt][0] += h[rt][sp][0]; Qa[rt][0] += h[rt][sp][0] * h[rt][sp][0];
      Sa[rt][1] += h[rt][sp][1]; Qa[rt][1] += h[rt][sp][1] * h[rt][sp][1];
      Sa[rt][2] += h[rt][sp][2]; Qa[rt][2] += h[rt][sp][2] * h[rt][sp][2];
      Sa[rt][3] += h[rt][sp][3]; Qa[rt][3] += h[rt][sp][3] * h[rt][sp][3];
    }
  }
  const int slot = blockIdx.x & 63;
  #pragma unroll
  for (int rt = 0; rt < 4; ++rt)
    #pragma unroll
    for (int r = 0; r < 4; ++r) {
      float S = Sa[rt][r], Q = Qa[rt][r];
      S += __shfl_xor(S, 1); S += __shfl_xor(S, 2); S += __shfl_xor(S, 4); S += __shfl_xor(S, 8);
      Q += __shfl_xor(Q, 1); Q += __shfl_xor(Q, 2); Q += __shfl_xor(Q, 4); Q += __shfl_xor(Q, 8);
      if (c == 0) {
        const int ch = oh * 64 + rt * 16 + 4 * g + r;
        atomicAdd(&ws[OFF_PS2 + slot * 128 + ch], S);
        atomicAdd(&ws[OFF_PQ2 + slot * 128 + ch], Q);
      }
    }
  __syncthreads();   // all A-phase LDS reads done block-wide
  // Hbuf[n'][o] stride 136, per item slot
  {
    ushortT* hb = &Tt[ib * 9216];
    #pragma unroll
    for (int rt = 0; rt < 4; ++rt)
      #pragma unroll
      for (int sp = 0; sp < 4; ++sp)
        *(uint2*)&hb[(sp * 16 + c) * 136 + oh * 64 + rt * 16 + 4 * g] = pack4(h[rt][sp]);
  }
  __syncthreads();
  // cooperative coalesced store: thread = half-row 128B
  {
    const int ib2 = t >> 7, n2 = (t >> 1) & 63, half = t & 1;
    const uint4* srcp = (const uint4*)&Tt[ib2 * 9216 + n2 * 136 + half * 64];
    uint4* dstp = (uint4*)(U + UOFF_H2 + (size_t)(b0 + ib2) * 8192 + n2 * 128 + half * 64);
    #pragma unroll
    for (int j = 0; j < 8; ++j) dstp[j] = srcp[j];
  }
}

// ---------------- layer 3 (+ mean pool): out[b] = (amean@relu(bn2(h2[b])))@W3 + b3 ----------------
__global__ __launch_bounds__(256) void layer3_kernel(const float* __restrict__ W3,
    const float* __restrict__ b3, const float* __restrict__ ws,
    float* __restrict__ out) {
  const int w = threadIdx.x >> 6, lane = threadIdx.x & 63;
  const int item = blockIdx.x * 4 + w;
  const int f0 = lane * 2;
  const float s2a = ws[OFF_SS2 + f0],       s2b = ws[OFF_SS2 + f0 + 1];
  const float t2a = ws[OFF_SS2 + 128 + f0], t2b = ws[OFF_SS2 + 128 + f0 + 1];
  const float* am = ws + OFF_AMEAN;
  const ushortT* h2 = (const ushortT*)(ws + 29120) + UOFF_H2 + (size_t)item * 8192;
  float v0 = 0.0f, v1 = 0.0f;
  #pragma unroll 8
  for (int m = 0; m < 64; ++m) {
    uintT pk = *(const uintT*)(h2 + m * 128 + f0);
    float y0 = fmaxf(fmaf(bf2f((ushortT)(pk & 0xffffu)), s2a, t2a), 0.0f);
    float y1 = fmaxf(fmaf(bf2f((ushortT)(pk >> 16)),     s2b, t2b), 0.0f);
    float a = am[m];
    v0 = fmaf(a, y0, v0);
    v1 = fmaf(a, y1, v1);
  }
  float o0 = b3[f0], o1 = b3[f0 + 1];
  #pragma unroll 8
  for (int k = 0; k < 128; ++k) {
    float vk = __shfl((k & 1) ? v1 : v0, k >> 1, 64);
    o0 = fmaf(vk, W3[k * 128 + f0],     o0);
    o1 = fmaf(vk, W3[k * 128 + f0 + 1], o1);
  }
  float2 ov; ov.x = o0; ov.y = o1;
  *(float2*)(out + (size_t)item * 128 + f0) = ov;
}

extern "C" void kernel_launch(void* const* d_in, const int* in_sizes, int n_in,
                              void* d_out, int out_size, void* d_ws, size_t ws_size,
                              hipStream_t stream) {
  const float* x   = (const float*)d_in[0];
  const float* W1  = (const float*)d_in[1];
  const float* b1  = (const float*)d_in[2];
  const float* W2  = (const float*)d_in[3];
  const float* b2  = (const float*)d_in[4];
  const float* W3  = (const float*)d_in[5];
  const float* b3  = (const float*)d_in[6];
  const float* g1  = (const float*)d_in[7];
  const float* be1 = (const float*)d_in[8];
  const float* g2  = (const float*)d_in[9];
  const float* be2 = (const float*)d_in[10];
  const int*   src = (const int*)d_in[11];
  const int*   dst = (const int*)d_in[12];
  const int E = in_sizes[11];
  float* ws  = (float*)d_ws;
  float* out = (float*)d_out;

  // zero BN partial-stat slots (PS1..PQ2)
  hipMemsetAsync((void*)(ws + OFF_PS1), 0, (size_t)(29120 - OFF_PS1) * 4, stream);
  hipLaunchKernelGGL(prep_kernel,    dim3(1),   dim3(256), 0, stream, src, dst, E, W1, W2, ws);
  hipLaunchKernelGGL(layer1_fused,   dim3(256), dim3(512), 0, stream, x, b1, ws);
  hipLaunchKernelGGL(reduce1_kernel, dim3(1),   dim3(64),  0, stream, g1, be1, ws);
  hipLaunchKernelGGL(layer2_fused,   dim3(512), dim3(512), 0, stream, b2, ws);
  hipLaunchKernelGGL(reduce2_kernel, dim3(1),   dim3(128), 0, stream, g2, be2, ws);
  hipLaunchKernelGGL(layer3_kernel,  dim3(512), dim3(256), 0, stream, W3, b3, ws, out);
}